// Round 8
// baseline (353.635 us; speedup 1.0000x reference)
//
#include <hip/hip_runtime.h>
#include <stdint.h>

// LSTMModel via MFMA (f16 weights/h, fp32 acc/c): 2-layer LSTM (H1=50, H2=64),
// B=2048, T=512 + FC 64->32->16->1.
//
// Round 8 = Round 7 + LDS bank-touch reduction:
//  - PAD-COL ALIASING: H buffers hold only the 8 real batch cols; lanes nn>=8
//    read col (nn&7) -> identical addresses as lanes nn-8 = HW broadcast.
//    Distinct bytes per b128 read halve; pad-col MFMA outputs were discarded
//    by dppsel anyway.
//  - H2 base +16B: +4-bank skew so the two lane-halves' h-write streams hit
//    disjoint banks (previously identical bank classes).
//  - Unconditional h-writes (waves 13..15 lower-lane garbage h1[52..63] is
//    annihilated by zeroed A k-columns; values provably finite).
// Structure (R5/R7): 256 blocks x 1024 threads (16 waves), Nb=8, skewed
// pipeline (layer2 one step behind), ONE barrier/step, dppsel redistribution,
// x prefetched one 8-step block ahead.
// Invariant: h1(tau) in H1[(tau+1)&1], h2(tau) in H2[(tau+1)&1]. At iter t
// (cur=t&1): read h1(t-1)=H1[cur], h2(t-2)=H2[cur^1]; write h1(t)->H1[cur^1]
// (lanes nn<8), h2(t-1)->H2[cur] (lanes nn>=8). t=0 forces c2=0 (h2(-1)=0).

typedef _Float16 f16x8 __attribute__((ext_vector_type(8)));
typedef float f32x4 __attribute__((ext_vector_type(4)));

#define TLEN 512
#define STG 0            // 256x64 f16 staging = 32768 B (later: FC scratch)
#define H1OFF 32768      // 2 bufs x 8 rows x 144 B = 2304
#define HSTR 144
#define HBUF 1152        // one buffer = 8*144
#define H2OFF 35088      // 32768 + 2304 + 16 (bank skew)
#define LDSB 37392

__device__ __forceinline__ float rcpf_(float x) {
#if __has_builtin(__builtin_amdgcn_rcpf)
  return __builtin_amdgcn_rcpf(x);
#else
  return __fdividef(1.0f, x);
#endif
}
__device__ __forceinline__ float sigf(float z)   { return rcpf_(1.0f + __expf(-z)); }
__device__ __forceinline__ float tanhf_(float z) { return 1.0f - 2.0f * rcpf_(1.0f + __expf(2.0f * z)); }

// lanes in banks 2,3 of each 16-lane DPP row (nn>=8) get dv from lane^8;
// lanes nn<8 keep av. row_ror:8 == xor-8 within a 16-lane row.
__device__ __forceinline__ float dppsel(float av, float dv) {
  return __int_as_float(__builtin_amdgcn_update_dpp(
      __float_as_int(av), __float_as_int(dv),
      0x128 /*row_ror:8*/, 0xF /*row_mask*/, 0xC /*bank_mask: banks 2,3*/, false));
}

#define MFMA16(A, B, C) __builtin_amdgcn_mfma_f32_16x16x32_f16(A, B, C, 0, 0, 0)

__global__ __launch_bounds__(1024, 1)
void lstm_mfma(const float* __restrict__ x,
               const float* __restrict__ w_ih1, const float* __restrict__ w_hh1,
               const float* __restrict__ b_ih1, const float* __restrict__ b_hh1,
               const float* __restrict__ w_ih2, const float* __restrict__ w_hh2,
               const float* __restrict__ b_ih2, const float* __restrict__ b_hh2,
               const float* __restrict__ fc1_w, const float* __restrict__ fc1_b,
               const float* __restrict__ fc2_w, const float* __restrict__ fc2_b,
               const float* __restrict__ fc3_w, const float* __restrict__ fc3_b,
               float* __restrict__ out)
{
  __shared__ __align__(16) char smem[LDSB];
  const int tid = threadIdx.x;
  const int wv = tid >> 6, ln = tid & 63;
  const int nn = ln & 15, g = ln >> 4;
  const int u = wv * 4 + g;               // this lane's unit (both layers)
  const bool isUpper = (nn >= 8);         // upper half-cols: layer-2 duty
  const bool hasL1 = (wv <= 12);          // waves 13..15: layer-1 tile is all zero

  _Float16* stg = (_Float16*)(smem + STG);
  f16x8 A1[2], A2i[2], A2h[2];

  // ---- stage + load A-fragments (gate-interleaved rows 4v+q, zero-padded) ----
  for (int idx = tid; idx < 16384; idx += 1024) {
    int R = idx >> 6, k = idx & 63, v = R >> 2, q = R & 3;
    stg[idx] = (_Float16)((v < 50 && k < 50) ? w_hh1[(q * 50 + v) * 50 + k] : 0.f);
  }
  __syncthreads();
  {
    int base = (wv * 16 + nn) * 128 + g * 16;
    A1[0] = *(const f16x8*)(smem + STG + base);
    A1[1] = *(const f16x8*)(smem + STG + base + 64);
  }
  __syncthreads();
  for (int idx = tid; idx < 16384; idx += 1024) {
    int R = idx >> 6, k = idx & 63, v = R >> 2, q = R & 3;
    stg[idx] = (_Float16)((k < 50) ? w_ih2[(q * 64 + v) * 50 + k] : 0.f);
  }
  __syncthreads();
  {
    int base = (wv * 16 + nn) * 128 + g * 16;
    A2i[0] = *(const f16x8*)(smem + STG + base);
    A2i[1] = *(const f16x8*)(smem + STG + base + 64);
  }
  __syncthreads();
  for (int idx = tid; idx < 16384; idx += 1024) {
    int R = idx >> 6, k = idx & 63, v = R >> 2, q = R & 3;
    stg[idx] = (_Float16)(w_hh2[(q * 64 + v) * 64 + k]);
  }
  // zero H1+H2 region: (LDSB - H1OFF) = 4624 B = 1156 dwords
  for (int i = tid; i < 1156; i += 1024) ((uint32_t*)(smem + H1OFF))[i] = 0;
  __syncthreads();
  {
    int base = (wv * 16 + nn) * 128 + g * 16;
    A2h[0] = *(const f16x8*)(smem + STG + base);
    A2h[1] = *(const f16x8*)(smem + STG + base + 64);
  }
  __syncthreads();

  // ---- per-lane constants for unit u ----
  float w1c[4], b1c[4];
  f32x4 b2v;
#pragma unroll
  for (int q = 0; q < 4; ++q) {
    bool r1 = (u < 50);
    w1c[q] = r1 ? w_ih1[q * 50 + u] : 0.f;
    b1c[q] = r1 ? (b_ih1[q * 50 + u] + b_hh1[q * 50 + u]) : 0.f;
    b2v[q] = b_ih2[q * 64 + u] + b_hh2[q * 64 + u];
  }

  const float* xp = x + (blockIdx.x * 8 + (nn & 7)) * TLEN;

  // write pointers for cur=0 / cur=1 (lower: h1(t)->H1[cur^1]; upper: h2(t-1)->H2[cur])
  _Float16 *wp0, *wp1;
  if (!isUpper) {
    wp0 = (_Float16*)(smem + H1OFF + HBUF + nn * HSTR + u * 2);
    wp1 = (_Float16*)(smem + H1OFF +    0 + nn * HSTR + u * 2);
  } else {
    wp0 = (_Float16*)(smem + H2OFF +    0 + (nn - 8) * HSTR + u * 2);
    wp1 = (_Float16*)(smem + H2OFF + HBUF + (nn - 8) * HSTR + u * 2);
  }

  // ALIASED read bases: all lanes read the real col (nn&7) -> broadcast pairs
  const char* const h1b = smem + H1OFF + (nn & 7) * HSTR;
  const char* const h2b = smem + H2OFF + (nn & 7) * HSTR;

  float cs = 0.f;                       // c1 (lower lanes) or c2 (upper lanes)
  f32x4 acc = {0.f, 0.f, 0.f, 0.f};     // layer-1 z (stays 0 for waves 13..15)

  // x double-buffer: current 8 steps in (xa,xb), next 8 prefetched into (na,nb)
  float4 xa = *(const float4*)&xp[0];
  float4 xb = *(const float4*)&xp[4];

  for (int tb = 0; tb < TLEN; tb += 8) {
    float4 na = {0.f, 0.f, 0.f, 0.f}, nb = {0.f, 0.f, 0.f, 0.f};
    if (tb + 8 < TLEN) {
      na = *(const float4*)&xp[tb + 8];
      nb = *(const float4*)&xp[tb + 12];
    }
    const float x8[8] = {xa.x, xa.y, xa.z, xa.w, xb.x, xb.y, xb.z, xb.w};
#pragma unroll
    for (int k = 0; k < 8; ++k) {
      const int cur = k & 1;
      const bool first = (tb == 0) && (k == 0);

      const f16x8 b0 = *(const f16x8*)(h1b + cur * HBUF + g * 16);
      const f16x8 b1 = *(const f16x8*)(h1b + cur * HBUF + 64 + g * 16);
      const f16x8 q0 = *(const f16x8*)(h2b + (cur ^ 1) * HBUF + g * 16);
      const f16x8 q1 = *(const f16x8*)(h2b + (cur ^ 1) * HBUF + 64 + g * 16);

      // layer-2 chain (all lanes), C seeded with bias
      f32x4 d = MFMA16(A2i[0], b0, b2v);
      d = MFMA16(A2i[1], b1, d);
      d = MFMA16(A2h[0], q0, d);
      d = MFMA16(A2h[1], q1, d);

      // layer-1 chain (waves 0..12), C seeded with w_ih1*x + bias
      if (hasL1) {
        const float xv = x8[k];
        f32x4 s;
        s[0] = fmaf(w1c[0], xv, b1c[0]);
        s[1] = fmaf(w1c[1], xv, b1c[1]);
        s[2] = fmaf(w1c[2], xv, b1c[2]);
        s[3] = fmaf(w1c[3], xv, b1c[3]);
        acc = MFMA16(A1[0], b0, s);
        acc = MFMA16(A1[1], b1, acc);
      }

      // fused permute+select: lower lanes keep acc (L1 z), upper get d from lane^8
      const float z0 = dppsel(acc[0], d[0]);
      const float z1 = dppsel(acc[1], d[1]);
      const float z2 = dppsel(acc[2], d[2]);
      const float z3 = dppsel(acc[3], d[3]);

      // one unit-update per lane: i,f,g,o -> c,h
      const float gi = sigf(z0), gf = sigf(z1), gg = tanhf_(z2), go = sigf(z3);
      float c = gf * cs + gi * gg;
      if (first) { if (isUpper) c = 0.f; }   // h2(-1)=0
      cs = c;
      const float h = go * tanhf_(c);
      *(cur ? wp1 : wp0) = (_Float16)h;
      __syncthreads();   // the ONE barrier per step
    }
    xa = na; xb = nb;
  }

  // ---- epilogue: h2(511) from h1(511)=H1[0], h2(510)=H2[1] ----
  {
    const f16x8 b0 = *(const f16x8*)(h1b + g * 16);
    const f16x8 b1 = *(const f16x8*)(h1b + 64 + g * 16);
    const f16x8 q0 = *(const f16x8*)(h2b + HBUF + g * 16);
    const f16x8 q1 = *(const f16x8*)(h2b + HBUF + 64 + g * 16);
    f32x4 d = MFMA16(A2i[0], b0, b2v);
    d = MFMA16(A2i[1], b1, d);
    d = MFMA16(A2h[0], q0, d);
    d = MFMA16(A2h[1], q1, d);
    const float dr0 = dppsel(0.f, d[0]);
    const float dr1 = dppsel(0.f, d[1]);
    const float dr2 = dppsel(0.f, d[2]);
    const float dr3 = dppsel(0.f, d[3]);
    if (isUpper) {
      const float gi = sigf(dr0), gf = sigf(dr1), gg = tanhf_(dr2), go = sigf(dr3);
      const float c = gf * cs + gi * gg;
      const float h = go * tanhf_(c);
      ((float*)smem)[(nn - 8) * 64 + u] = h;   // fp32 h2(511): [8][64]
    }
  }
  __syncthreads();

  // ---- FC head: 64 -> 32 -> 16 -> 1 ----
  float* h2f = (float*)smem;                 // [8][64]
  float* f1o = (float*)(smem + 4096);        // [8][32]
  float* f2o = (float*)(smem + 4096 + 1024); // [8][16]
  if (tid < 256) {
    int o = tid & 31, n = tid >> 5;
    float s = fc1_b[o];
#pragma unroll 8
    for (int k = 0; k < 64; ++k) s = fmaf(h2f[n * 64 + k], fc1_w[o * 64 + k], s);
    f1o[n * 32 + o] = s;
  }
  __syncthreads();
  if (tid < 128) {
    int o = tid & 15, n = tid >> 4;
    float s = fc2_b[o];
#pragma unroll 8
    for (int k = 0; k < 32; ++k) s = fmaf(f1o[n * 32 + k], fc2_w[o * 32 + k], s);
    f2o[n * 16 + o] = s;
  }
  __syncthreads();
  if (tid < 8) {
    float s = fc3_b[0];
#pragma unroll
    for (int k = 0; k < 16; ++k) s = fmaf(f2o[tid * 16 + k], fc3_w[k], s);
    out[blockIdx.x * 8 + tid] = s;
  }
}

extern "C" void kernel_launch(void* const* d_in, const int* in_sizes, int n_in,
                              void* d_out, int out_size, void* d_ws, size_t ws_size,
                              hipStream_t stream) {
  const float* x     = (const float*)d_in[0];
  const float* w_ih1 = (const float*)d_in[1];
  const float* w_hh1 = (const float*)d_in[2];
  const float* b_ih1 = (const float*)d_in[3];
  const float* b_hh1 = (const float*)d_in[4];
  const float* w_ih2 = (const float*)d_in[5];
  const float* w_hh2 = (const float*)d_in[6];
  const float* b_ih2 = (const float*)d_in[7];
  const float* b_hh2 = (const float*)d_in[8];
  const float* fc1_w = (const float*)d_in[9];
  const float* fc1_b = (const float*)d_in[10];
  const float* fc2_w = (const float*)d_in[11];
  const float* fc2_b = (const float*)d_in[12];
  const float* fc3_w = (const float*)d_in[13];
  const float* fc3_b = (const float*)d_in[14];

  hipLaunchKernelGGL(lstm_mfma, dim3(256), dim3(1024), 0, stream,
                     x, w_ih1, w_hh1, b_ih1, b_hh1,
                     w_ih2, w_hh2, b_ih2, b_hh2,
                     fc1_w, fc1_b, fc2_w, fc2_b, fc3_w, fc3_b,
                     (float*)d_out);
}

// Round 9
// 259.696 us; speedup vs baseline: 1.3617x; 1.3617x over previous
//
#include <hip/hip_runtime.h>
#include <stdint.h>

// LSTMModel via MFMA (f16 weights/h, fp32 acc/c): 2-layer LSTM (H1=50, H2=64),
// B=2048, T=512 + FC 64->32->16->1.
//
// Round 9 = Round 8 + wave CLASS SPLIT + exp2 pre-scaling + setprio:
//  - Waves 0-7: LAYER-1 duty. Read only b0,b1 (h1(t-1)) = 2 ds_read_b128;
//    4 MFMA (wave 7: both tiles pad -> skip); seed C with fma(w_ih1*x+bias).
//  - Waves 8-15: LAYER-2 duty. Read b0,b1 + q0,q1 (h2(t-2)) = 4 ds_reads;
//    8 MFMA (2 tiles x 4-chain), C seeded with bias; s_setprio(1) around the
//    MFMA cluster (T5: class split creates the role diversity setprio needs).
//  Total 48 ds_read_b128/step/CU vs 64 (-25% LDS pipe). Each lane still does
//  exactly ONE unit-update (dppsel half-split as R7/R8). L1/L2 frags share
//  registers (classes are disjoint) to stay under the 128-VGPR cap.
//  - exp2 PRE-SCALING: gate rows i,f,o scaled by -log2e, gate g by +2*log2e
//    at staging (weights, biases, x-seed) -> sigmoid = rcp(1+exp2(z')),
//    tanh = 1-2*rcp(1+exp2(z')): saves 4 v_mul per update. v_exp_f32 IS exp2.
// Structure: 256 blocks x 1024 threads, Nb=8, skewed pipeline (layer2 one step
// behind), ONE barrier/step, x prefetched one 8-step block ahead (L1 waves).
// Invariant: h1(tau) in H1[(tau+1)&1], h2(tau) in H2[(tau+1)&1]. At iter t
// (cur=t&1): read h1(t-1)=H1[cur], h2(t-2)=H2[cur^1]; write h1(t)->H1[cur^1]
// (L1 waves), h2(t-1)->H2[cur] (L2 waves). t=0 forces c2=0 (h2(-1)=0).

typedef _Float16 f16x8 __attribute__((ext_vector_type(8)));
typedef float f32x4 __attribute__((ext_vector_type(4)));

#define TLEN 512
#define STG 0            // 256x64 f16 staging = 32768 B (later: FC scratch)
#define H1OFF 32768      // 2 bufs x 8 rows x 144 B = 2304
#define HSTR 144
#define HBUF 1152        // one buffer = 8*144
#define H2OFF 35088      // 32768 + 2304 + 16 (bank skew)
#define LDSB 37392

#define NLOG2E -1.4426950408889634f
#define TLOG2E  2.8853900817779268f   // +2*log2e

__device__ __forceinline__ float rcpf_(float x) {
#if __has_builtin(__builtin_amdgcn_rcpf)
  return __builtin_amdgcn_rcpf(x);
#else
  return __fdividef(1.0f, x);
#endif
}
__device__ __forceinline__ float exp2_(float x) {
#if __has_builtin(__builtin_amdgcn_exp2f)
  return __builtin_amdgcn_exp2f(x);
#else
  return exp2f(x);
#endif
}

// lanes with (lane mod 16) >= 8 get dv from lane^8; lanes nn<8 keep av.
__device__ __forceinline__ float dppsel(float av, float dv) {
  return __int_as_float(__builtin_amdgcn_update_dpp(
      __float_as_int(av), __float_as_int(dv),
      0x128 /*row_ror:8*/, 0xF /*row_mask*/, 0xC /*bank_mask*/, false));
}

#define MFMA16(A, B, C) __builtin_amdgcn_mfma_f32_16x16x32_f16(A, B, C, 0, 0, 0)

__global__ __launch_bounds__(1024, 1)
void lstm_mfma(const float* __restrict__ x,
               const float* __restrict__ w_ih1, const float* __restrict__ w_hh1,
               const float* __restrict__ b_ih1, const float* __restrict__ b_hh1,
               const float* __restrict__ w_ih2, const float* __restrict__ w_hh2,
               const float* __restrict__ b_ih2, const float* __restrict__ b_hh2,
               const float* __restrict__ fc1_w, const float* __restrict__ fc1_b,
               const float* __restrict__ fc2_w, const float* __restrict__ fc2_b,
               const float* __restrict__ fc3_w, const float* __restrict__ fc3_b,
               float* __restrict__ out)
{
  __shared__ __align__(16) char smem[LDSB];
  const int tid = threadIdx.x;
  const int wv = tid >> 6, ln = tid & 63;
  const int nn = ln & 15, g = ln >> 4;
  const bool isL2 = (wv >= 8);
  const int W = isL2 ? (wv - 8) : wv;       // class-local wave index (0..7)
  const int half = nn >> 3;                 // which of the 2 tiles this lane updates
  const int col = nn & 7;                   // batch col
  const int uA = W * 8 + half * 4 + g;      // this lane's update unit

  _Float16* stg = (_Float16*)(smem + STG);
  // gate-row scales: i,f,o -> -log2e ; g -> +2log2e
  const float SCQ[4] = {NLOG2E, NLOG2E, TLOG2E, NLOG2E};

  // F0: L1 = whh1 tiles / L2 = wih2 tiles.  F1: L2 = whh2 tiles (L1: unused).
  f16x8 F0[2][2], F1[2][2];
#pragma unroll
  for (int tl = 0; tl < 2; ++tl)
#pragma unroll
    for (int kf = 0; kf < 2; ++kf) F1[tl][kf] = (f16x8)(_Float16)0.f;

  // ---- phase A: stage whh1 (gate-interleaved rows 4v+q, scaled, padded) ----
  for (int idx = tid; idx < 16384; idx += 1024) {
    int R = idx >> 6, k = idx & 63, v = R >> 2, q = R & 3;
    stg[idx] = (_Float16)((v < 50 && k < 50) ? w_hh1[(q * 50 + v) * 50 + k] * SCQ[q] : 0.f);
  }
  __syncthreads();
  if (!isL2) {
#pragma unroll
    for (int tl = 0; tl < 2; ++tl) {
      int base = ((W * 2 + tl) * 16 + nn) * 128 + g * 16;
      F0[tl][0] = *(const f16x8*)(smem + STG + base);
      F0[tl][1] = *(const f16x8*)(smem + STG + base + 64);
    }
  }
  __syncthreads();
  // ---- phase B: stage wih2 ----
  for (int idx = tid; idx < 16384; idx += 1024) {
    int R = idx >> 6, k = idx & 63, v = R >> 2, q = R & 3;
    stg[idx] = (_Float16)((k < 50) ? w_ih2[(q * 64 + v) * 50 + k] * SCQ[q] : 0.f);
  }
  __syncthreads();
  if (isL2) {
#pragma unroll
    for (int tl = 0; tl < 2; ++tl) {
      int base = ((W * 2 + tl) * 16 + nn) * 128 + g * 16;
      F0[tl][0] = *(const f16x8*)(smem + STG + base);
      F0[tl][1] = *(const f16x8*)(smem + STG + base + 64);
    }
  }
  __syncthreads();
  // ---- phase C: stage whh2 + zero H buffers ----
  for (int idx = tid; idx < 16384; idx += 1024) {
    int R = idx >> 6, k = idx & 63, v = R >> 2, q = R & 3;
    stg[idx] = (_Float16)(w_hh2[(q * 64 + v) * 64 + k] * SCQ[q]);
  }
  for (int i = tid; i < 1156; i += 1024) ((uint32_t*)(smem + H1OFF))[i] = 0;
  __syncthreads();
  if (isL2) {
#pragma unroll
    for (int tl = 0; tl < 2; ++tl) {
      int base = ((W * 2 + tl) * 16 + nn) * 128 + g * 16;
      F1[tl][0] = *(const f16x8*)(smem + STG + base);
      F1[tl][1] = *(const f16x8*)(smem + STG + base + 64);
    }
  }
  __syncthreads();

  // ---- per-lane C-seed constants (scaled): tile tl unit u = 8W+4tl+g ----
  float w1c[2][4], b1c[2][4];
#pragma unroll
  for (int tl = 0; tl < 2; ++tl) {
    int u = W * 8 + tl * 4 + g;
#pragma unroll
    for (int q = 0; q < 4; ++q) {
      if (!isL2) {
        bool r1 = (u < 50);
        w1c[tl][q] = r1 ? w_ih1[q * 50 + u] * SCQ[q] : 0.f;
        b1c[tl][q] = r1 ? (b_ih1[q * 50 + u] + b_hh1[q * 50 + u]) * SCQ[q] : 0.f;
      } else {
        w1c[tl][q] = 0.f;
        b1c[tl][q] = (b_ih2[q * 64 + u] + b_hh2[q * 64 + u]) * SCQ[q];
      }
    }
  }
  const bool l1mfma = (!isL2) && (wv < 7);     // wave 7: both L1 tiles pad
  const bool doWrite = (wv != 7);

  const float* xp = x + (blockIdx.x * 8 + col) * TLEN;

  // write pointers (cur=0 / cur=1). L1: h1(t)->H1[cur^1]; L2: h2(t-1)->H2[cur].
  _Float16 *wp0, *wp1;
  if (!isL2) {
    wp0 = (_Float16*)(smem + H1OFF + HBUF + col * HSTR + uA * 2);
    wp1 = (_Float16*)(smem + H1OFF +    0 + col * HSTR + uA * 2);
  } else {
    wp0 = (_Float16*)(smem + H2OFF +    0 + col * HSTR + uA * 2);
    wp1 = (_Float16*)(smem + H2OFF + HBUF + col * HSTR + uA * 2);
  }

  // aliased read bases (all lanes read real col nn&7 -> broadcast pairs)
  const char* const h1b = smem + H1OFF + col * HSTR;
  const char* const h2b = smem + H2OFF + col * HSTR;

  float cs = 0.f;                 // c1 (L1 waves) or c2 (L2 waves)

  float4 xa = {0.f,0.f,0.f,0.f}, xb = {0.f,0.f,0.f,0.f};
  if (!isL2) { xa = *(const float4*)&xp[0]; xb = *(const float4*)&xp[4]; }

  for (int tb = 0; tb < TLEN; tb += 8) {
    float4 na = {0.f,0.f,0.f,0.f}, nb = {0.f,0.f,0.f,0.f};
    if (!isL2 && tb + 8 < TLEN) {
      na = *(const float4*)&xp[tb + 8];
      nb = *(const float4*)&xp[tb + 12];
    }
#pragma unroll
    for (int k = 0; k < 8; ++k) {
      const int cur = k & 1;
      const bool first = (tb == 0) && (k == 0);

      const f16x8 b0 = *(const f16x8*)(h1b + cur * HBUF + g * 16);
      const f16x8 b1 = *(const f16x8*)(h1b + cur * HBUF + 64 + g * 16);

      f32x4 a0, a1;
      if (!isL2) {
        // layer-1: seed = w_ih1*x + bias (scaled), + Whh1 . h1(t-1)
        const float xv = (k < 4) ? ((const float*)&xa)[k] : ((const float*)&xb)[k - 4];
        f32x4 s0, s1;
        s0[0] = fmaf(w1c[0][0], xv, b1c[0][0]);
        s0[1] = fmaf(w1c[0][1], xv, b1c[0][1]);
        s0[2] = fmaf(w1c[0][2], xv, b1c[0][2]);
        s0[3] = fmaf(w1c[0][3], xv, b1c[0][3]);
        s1[0] = fmaf(w1c[1][0], xv, b1c[1][0]);
        s1[1] = fmaf(w1c[1][1], xv, b1c[1][1]);
        s1[2] = fmaf(w1c[1][2], xv, b1c[1][2]);
        s1[3] = fmaf(w1c[1][3], xv, b1c[1][3]);
        a0 = s0; a1 = s1;
        if (l1mfma) {
          a0 = MFMA16(F0[0][0], b0, s0);  a0 = MFMA16(F0[0][1], b1, a0);
          a1 = MFMA16(F0[1][0], b0, s1);  a1 = MFMA16(F0[1][1], b1, a1);
        }
      } else {
        // layer-2: bias-seeded, Wih2 . h1(t-1) + Whh2 . h2(t-2)
        const f16x8 q0 = *(const f16x8*)(h2b + (cur ^ 1) * HBUF + g * 16);
        const f16x8 q1 = *(const f16x8*)(h2b + (cur ^ 1) * HBUF + 64 + g * 16);
        const f32x4 s0 = {b1c[0][0], b1c[0][1], b1c[0][2], b1c[0][3]};
        const f32x4 s1 = {b1c[1][0], b1c[1][1], b1c[1][2], b1c[1][3]};
        __builtin_amdgcn_s_setprio(1);
        a0 = MFMA16(F0[0][0], b0, s0);  a0 = MFMA16(F0[0][1], b1, a0);
        a0 = MFMA16(F1[0][0], q0, a0);  a0 = MFMA16(F1[0][1], q1, a0);
        a1 = MFMA16(F0[1][0], b0, s1);  a1 = MFMA16(F0[1][1], b1, a1);
        a1 = MFMA16(F1[1][0], q0, a1);  a1 = MFMA16(F1[1][1], q1, a1);
        __builtin_amdgcn_s_setprio(0);
      }

      // half-split: lanes nn<8 take tile0 (a0), nn>=8 take tile1 from lane^8
      const float z0 = dppsel(a0[0], a1[0]);
      const float z1 = dppsel(a0[1], a1[1]);
      const float z2 = dppsel(a0[2], a1[2]);
      const float z3 = dppsel(a0[3], a1[3]);

      // gates (args pre-scaled): i,f,o sigmoid; g tanh
      const float gi = rcpf_(1.0f + exp2_(z0));
      const float gf = rcpf_(1.0f + exp2_(z1));
      const float gg = 1.0f - 2.0f * rcpf_(1.0f + exp2_(z2));
      const float go = rcpf_(1.0f + exp2_(z3));
      float c = gf * cs + gi * gg;
      if (first && isL2) c = 0.f;      // h2(-1)=0
      cs = c;
      const float h = go * (1.0f - 2.0f * rcpf_(1.0f + exp2_(TLOG2E * c)));
      if (doWrite) *(cur ? wp1 : wp0) = (_Float16)h;
      __syncthreads();   // the ONE barrier per step
    }
    xa = na; xb = nb;
  }

  // ---- epilogue (L2 waves): h2(511) from h1(511)=H1[0], h2(510)=H2[1] ----
  if (isL2) {
    const f16x8 b0 = *(const f16x8*)(h1b + g * 16);
    const f16x8 b1 = *(const f16x8*)(h1b + 64 + g * 16);
    const f16x8 q0 = *(const f16x8*)(h2b + HBUF + g * 16);
    const f16x8 q1 = *(const f16x8*)(h2b + HBUF + 64 + g * 16);
    const f32x4 s0 = {b1c[0][0], b1c[0][1], b1c[0][2], b1c[0][3]};
    const f32x4 s1 = {b1c[1][0], b1c[1][1], b1c[1][2], b1c[1][3]};
    f32x4 a0 = MFMA16(F0[0][0], b0, s0);  a0 = MFMA16(F0[0][1], b1, a0);
    a0 = MFMA16(F1[0][0], q0, a0);  a0 = MFMA16(F1[0][1], q1, a0);
    f32x4 a1 = MFMA16(F0[1][0], b0, s1);  a1 = MFMA16(F0[1][1], b1, a1);
    a1 = MFMA16(F1[1][0], q0, a1);  a1 = MFMA16(F1[1][1], q1, a1);
    const float z0 = dppsel(a0[0], a1[0]);
    const float z1 = dppsel(a0[1], a1[1]);
    const float z2 = dppsel(a0[2], a1[2]);
    const float z3 = dppsel(a0[3], a1[3]);
    const float gi = rcpf_(1.0f + exp2_(z0));
    const float gf = rcpf_(1.0f + exp2_(z1));
    const float gg = 1.0f - 2.0f * rcpf_(1.0f + exp2_(z2));
    const float go = rcpf_(1.0f + exp2_(z3));
    const float c = gf * cs + gi * gg;
    const float h = go * (1.0f - 2.0f * rcpf_(1.0f + exp2_(TLOG2E * c)));
    ((float*)smem)[col * 64 + uA] = h;   // fp32 h2(511): [8][64]
  }
  __syncthreads();

  // ---- FC head: 64 -> 32 -> 16 -> 1 ----
  float* h2f = (float*)smem;                 // [8][64]
  float* f1o = (float*)(smem + 8192);        // [8][32]
  float* f2o = (float*)(smem + 8192 + 1024); // [8][16]
  if (tid < 256) {
    int o = tid & 31, n = tid >> 5;
    float s = fc1_b[o];
#pragma unroll 8
    for (int k = 0; k < 64; ++k) s = fmaf(h2f[n * 64 + k], fc1_w[o * 64 + k], s);
    f1o[n * 32 + o] = s;
  }
  __syncthreads();
  if (tid < 128) {
    int o = tid & 15, n = tid >> 4;
    float s = fc2_b[o];
#pragma unroll 8
    for (int k = 0; k < 32; ++k) s = fmaf(f1o[n * 32 + k], fc2_w[o * 32 + k], s);
    f2o[n * 16 + o] = s;
  }
  __syncthreads();
  if (tid < 8) {
    float s = fc3_b[0];
#pragma unroll
    for (int k = 0; k < 16; ++k) s = fmaf(f2o[tid * 16 + k], fc3_w[k], s);
    out[blockIdx.x * 8 + tid] = s;
  }
}

extern "C" void kernel_launch(void* const* d_in, const int* in_sizes, int n_in,
                              void* d_out, int out_size, void* d_ws, size_t ws_size,
                              hipStream_t stream) {
  const float* x     = (const float*)d_in[0];
  const float* w_ih1 = (const float*)d_in[1];
  const float* w_hh1 = (const float*)d_in[2];
  const float* b_ih1 = (const float*)d_in[3];
  const float* b_hh1 = (const float*)d_in[4];
  const float* w_ih2 = (const float*)d_in[5];
  const float* w_hh2 = (const float*)d_in[6];
  const float* b_ih2 = (const float*)d_in[7];
  const float* b_hh2 = (const float*)d_in[8];
  const float* fc1_w = (const float*)d_in[9];
  const float* fc1_b = (const float*)d_in[10];
  const float* fc2_w = (const float*)d_in[11];
  const float* fc2_b = (const float*)d_in[12];
  const float* fc3_w = (const float*)d_in[13];
  const float* fc3_b = (const float*)d_in[14];

  hipLaunchKernelGGL(lstm_mfma, dim3(256), dim3(1024), 0, stream,
                     x, w_ih1, w_hh1, b_ih1, b_hh1,
                     w_ih2, w_hh2, b_ih2, b_hh2,
                     fc1_w, fc1_b, fc2_w, fc2_b, fc3_w, fc3_b,
                     (float*)d_out);
}